// Round 12
// baseline (491.130 us; speedup 1.0000x reference)
//
#include <hip/hip_runtime.h>

#define NN 100000
#define NE 1600000
#define F 128
#define NBUCK ((NN + 255) >> 8)                         // 391 buckets of 256 nodes
#define EPB (NE / 256)                                  // 6250 edges per scatter block
#define PL ((size_t)NN * 16)                            // elements per 16-col slice plane

typedef _Float16 f16x8 __attribute__((ext_vector_type(8)));
typedef float    f32x4 __attribute__((ext_vector_type(4)));
typedef unsigned short ushort8v __attribute__((ext_vector_type(8)));
typedef unsigned short ushort4v __attribute__((ext_vector_type(4)));

__device__ inline unsigned short f2h(float f) {
    _Float16 h = (_Float16)f;                       // RTN
    return __builtin_bit_cast(unsigned short, h);
}
__device__ inline float h2f(unsigned short u) {
    return (float)__builtin_bit_cast(_Float16, u);
}

// ---------------- CSR build (bucket-level only) ----------------
__global__ __launch_bounds__(256) void k_bhist(const int* __restrict__ dst, int* __restrict__ bcnt) {
    __shared__ int sc[NBUCK];
    for (int i = threadIdx.x; i < NBUCK; i += 256) sc[i] = 0;
    __syncthreads();
    int stride = gridDim.x * 256;
    for (int e = blockIdx.x * 256 + threadIdx.x; e < NE; e += stride)
        atomicAdd(&sc[dst[e] >> 8], 1);
    __syncthreads();
    for (int i = threadIdx.x; i < NBUCK; i += 256) {
        int c = sc[i];
        if (c) atomicAdd(&bcnt[i], c);
    }
}

__global__ void k_bscan(const int* __restrict__ bcnt, int* __restrict__ bbase, int* __restrict__ bcur) {
    __shared__ int s[512];
    int t = threadIdx.x;
    int v = (t < NBUCK) ? bcnt[t] : 0;
    s[t] = v;
    __syncthreads();
    for (int off = 1; off < 512; off <<= 1) {
        int u = (t >= off) ? s[t - off] : 0;
        __syncthreads();
        s[t] += u;
        __syncthreads();
    }
    int excl = s[t] - v;
    if (t < NBUCK) { bbase[t] = excl; bcur[t] = excl; }
    if (t == 0) bbase[NBUCK] = NE;
}

__global__ __launch_bounds__(256) void k_scatterA(const int* __restrict__ src,
                                                  const int* __restrict__ dst,
                                                  int* __restrict__ bcur,
                                                  unsigned* __restrict__ scratch) {
    __shared__ uint2 sEdge[EPB];          // 50 KB
    __shared__ int cnt[512];
    __shared__ int scn[512];
    __shared__ int cntB[512];
    __shared__ int gbase[512];
    __shared__ int ssum[256];

    const int tid = threadIdx.x;
    const int ebase = blockIdx.x * EPB;

#pragma unroll
    for (int i = tid; i < 512; i += 256) { cnt[i] = 0; cntB[i] = 0; }
    __syncthreads();

    for (int i = tid; i < EPB; i += 256) {
        int b = dst[ebase + i] >> 8;
        atomicAdd(&cnt[b], 1);
    }
    __syncthreads();

    int c0 = cnt[2 * tid], c1 = cnt[2 * tid + 1];
    ssum[tid] = c0 + c1;
    __syncthreads();
    for (int off = 1; off < 256; off <<= 1) {
        int v = (tid >= off) ? ssum[tid - off] : 0;
        __syncthreads();
        ssum[tid] += v;
        __syncthreads();
    }
    int texcl = (tid == 0) ? 0 : ssum[tid - 1];
    scn[2 * tid] = texcl;
    scn[2 * tid + 1] = texcl + c0;
#pragma unroll
    for (int i = tid; i < NBUCK; i += 256) {
        int c = cnt[i];
        gbase[i] = c ? atomicAdd(&bcur[i], c) : 0;
    }
    __syncthreads();

    for (int i = tid; i < EPB; i += 256) {
        int s = src[ebase + i], d = dst[ebase + i];
        int b = d >> 8;
        int rank = atomicAdd(&cntB[b], 1);
        sEdge[scn[b] + rank] = make_uint2((unsigned)s, (unsigned)d);
    }
    __syncthreads();

    for (int i = tid; i < EPB; i += 256) {
        uint2 ed = sEdge[i];
        int b = (int)(ed.y >> 8);
        unsigned w = ((ed.y & 255u) << 24) | ed.x;
        scratch[gbase[b] + (i - scn[b])] = w;
    }
}

__global__ __launch_bounds__(256) void k_fillB(const int* __restrict__ bbase,
                                               const unsigned* __restrict__ scratch,
                                               int* __restrict__ row_ptr,
                                               int* __restrict__ csr) {
    __shared__ int cnt[256];
    __shared__ int s[256];
    __shared__ int cur[256];
    int b = blockIdx.x;
    int base = bbase[b], end = bbase[b + 1];
    int t = threadIdx.x;
    cnt[t] = 0;
    __syncthreads();
    for (int i = base + t; i < end; i += 256)
        atomicAdd(&cnt[scratch[i] >> 24], 1);
    __syncthreads();
    int v = cnt[t];
    s[t] = v;
    __syncthreads();
    for (int off = 1; off < 256; off <<= 1) {
        int u = (t >= off) ? s[t - off] : 0;
        __syncthreads();
        s[t] += u;
        __syncthreads();
    }
    int excl = s[t] - v;
    int node = (b << 8) + t;
    if (node < NN) row_ptr[node] = base + excl;
    if (b == NBUCK - 1 && t == 0) row_ptr[NN] = NE;
    cur[t] = excl;
    __syncthreads();
    for (int i = base + t; i < end; i += 256) {
        unsigned w = scratch[i];
        int n = w >> 24;
        int p = atomicAdd(&cur[n], 1);
        csr[base + p] = (int)(w & 0xFFFFFFu);
    }
}

// ---------------- x -> fp16 slice planes ----------------
// plane s (0..7) holds cols [16s,16s+16) of all nodes, contiguous by node.
__global__ void k_x2h(const float* __restrict__ x, unsigned short* __restrict__ xh) {
    int i = blockIdx.x * 256 + threadIdx.x;       // over NN*16 granules of 8 cols (exact)
    int n = i >> 4, g = i & 15;
    int s = g >> 1, hh = g & 1;
    const float4* src = (const float4*)(x + (size_t)n * F + g * 8);
    float4 v0 = src[0], v1 = src[1];
    ushort8v o;
    o[0] = f2h(v0.x); o[1] = f2h(v0.y); o[2] = f2h(v0.z); o[3] = f2h(v0.w);
    o[4] = f2h(v1.x); o[5] = f2h(v1.y); o[6] = f2h(v1.z); o[7] = f2h(v1.w);
    *(ushort8v*)&xh[(size_t)s * PL + (size_t)n * 16 + hh * 8] = o;
}

// ---------------- weight: W[k][n] fp32 -> Wt [n][k] fp16 ----------------
struct WPack {
    const float* w[5];
    unsigned short* t[5];
};

__global__ void k_w2h(WPack p) {
    int which = blockIdx.x >> 6;
    int idx = (blockIdx.x & 63) * 256 + threadIdx.x; // over n*128+k
    int n = idx >> 7, k = idx & 127;
    p.t[which][idx] = f2h(p.w[which][k * 128 + n]);
}

// ---------------- aggregation: feature-sliced, XCD-affine ----------------
// slice = blockIdx & 7 -> (heuristically) one XCD per slice; plane = 3.2 MB, L2-resident.
// 2 lanes per node row (16 B each), 128 rows per block, 8-way neighbor unroll.
__global__ __launch_bounds__(256) void k_agg(const unsigned short* __restrict__ h,
                                             const int* __restrict__ row_ptr,
                                             const int* __restrict__ csr,
                                             unsigned short* __restrict__ u) {
    const int s  = blockIdx.x & 7;
    const int nb = blockIdx.x >> 3;
    const int rl = threadIdx.x >> 1;
    const int hh = threadIdx.x & 1;
    const int node = nb * 128 + rl;
    if (node >= NN) return;
    const unsigned short* P = h + (size_t)s * PL;
    unsigned short* Q = u + (size_t)s * PL;
    const size_t base = (size_t)node * 16 + hh * 8;
    ushort8v sh = *(const ushort8v*)&P[base];
    float a[8];
#pragma unroll
    for (int k = 0; k < 8; ++k) a[k] = h2f(sh[k]);
    int st = row_ptr[node], e = row_ptr[node + 1];
    int p = st;
    const int ho = hh * 8;
    for (; p + 8 <= e; p += 8) {
        ushort8v v[8];
#pragma unroll
        for (int q = 0; q < 8; ++q) {
            int j = csr[p + q];
            v[q] = *(const ushort8v*)&P[(size_t)j * 16 + ho];
        }
#pragma unroll
        for (int k = 0; k < 8; ++k) {
            float t0 = (h2f(v[0][k]) + h2f(v[1][k])) + (h2f(v[2][k]) + h2f(v[3][k]));
            float t1 = (h2f(v[4][k]) + h2f(v[5][k])) + (h2f(v[6][k]) + h2f(v[7][k]));
            a[k] += t0 + t1;
        }
    }
    if (p + 4 <= e) {
        ushort8v v[4];
#pragma unroll
        for (int q = 0; q < 4; ++q) {
            int j = csr[p + q];
            v[q] = *(const ushort8v*)&P[(size_t)j * 16 + ho];
        }
#pragma unroll
        for (int k = 0; k < 8; ++k)
            a[k] += (h2f(v[0][k]) + h2f(v[1][k])) + (h2f(v[2][k]) + h2f(v[3][k]));
        p += 4;
    }
    if (p + 2 <= e) {
        int j0 = csr[p], j1 = csr[p + 1];
        ushort8v v0 = *(const ushort8v*)&P[(size_t)j0 * 16 + ho];
        ushort8v v1 = *(const ushort8v*)&P[(size_t)j1 * 16 + ho];
#pragma unroll
        for (int k = 0; k < 8; ++k) a[k] += h2f(v0[k]) + h2f(v1[k]);
        p += 2;
    }
    if (p < e) {
        int j0 = csr[p];
        ushort8v v0 = *(const ushort8v*)&P[(size_t)j0 * 16 + ho];
#pragma unroll
        for (int k = 0; k < 8; ++k) a[k] += h2f(v0[k]);
    }
    ushort8v o;
#pragma unroll
    for (int k = 0; k < 8; ++k) o[k] = f2h(a[k]);
    *(ushort8v*)&Q[base] = o;
}

// ---------------- MLP layer: 64-row tile, 4 col-slice waves; plane-layout I/O -------------
template <int L3>
__global__ __launch_bounds__(256, 6) void k_mlp(const unsigned short* __restrict__ A,
                                                const unsigned short* __restrict__ W1,
                                                const float* __restrict__ b1,
                                                const unsigned short* __restrict__ W2,
                                                const float* __restrict__ b2,
                                                const float* __restrict__ w32,
                                                const float* __restrict__ b32,
                                                unsigned short* __restrict__ H,
                                                float* __restrict__ out) {
    __shared__ __align__(16) unsigned short sA[64 * 128];   // 16 KB

    const int tid = threadIdx.x;
    const int row0 = blockIdx.x * 64;
    const int cg   = tid >> 6;           // wave id = col slice 0..3
    const int lane = tid & 63;
    const int m16  = lane & 15;
    const int quad = lane >> 4;

    // ---- stage A tile from 8 planes: unit = (s,r); coalesced 32 B per unit ----
#pragma unroll
    for (int it = 0; it < 2; ++it) {
        int unit = it * 256 + tid;        // 0..511
        int s = unit >> 6, r = unit & 63;
        int node = row0 + r;
        ushort8v v0 = {}, v1 = {};
        if (node < NN) {
            const unsigned short* P = A + (size_t)s * PL + (size_t)node * 16;
            v0 = *(const ushort8v*)&P[0];
            v1 = *(const ushort8v*)&P[8];
        }
        int u0 = 2 * s, u1 = 2 * s + 1;
        *(ushort8v*)&sA[r * 128 + ((u0 ^ (r & 15)) << 3)] = v0;
        *(ushort8v*)&sA[r * 128 + ((u1 ^ (r & 15)) << 3)] = v1;
    }
    __syncthreads();

    // ---- GEMM1 ----
    f32x4 acc[4][2] = {};
#pragma unroll
    for (int ks = 0; ks < 4; ++ks) {
        f16x8 a[4];
#pragma unroll
        for (int rt = 0; rt < 4; ++rt) {
            int rowL = rt * 16 + m16;
            int u = ks * 4 + quad;
            a[rt] = *(const f16x8*)&sA[rowL * 128 + ((u ^ (rowL & 15)) << 3)];
        }
#pragma unroll
        for (int ct = 0; ct < 2; ++ct) {
            int widx = (cg * 32 + ct * 16 + m16) * 128 + ks * 32 + quad * 8;
            f16x8 b = *(const f16x8*)&W1[widx];
#pragma unroll
            for (int rt = 0; rt < 4; ++rt)
                acc[rt][ct] = __builtin_amdgcn_mfma_f32_16x16x32_f16(a[rt], b, acc[rt][ct], 0, 0, 0);
        }
    }

    if (L3) {
        float* psf = (float*)sA;     // 64 rows x 4 cg
        __syncthreads();
#pragma unroll
        for (int rt = 0; rt < 4; ++rt) {
            float s[4] = {0.f, 0.f, 0.f, 0.f};
#pragma unroll
            for (int ct = 0; ct < 2; ++ct) {
                int col = cg * 32 + ct * 16 + m16;
                float bv = b1[col];
                float wv = w32[col];
#pragma unroll
                for (int i = 0; i < 4; ++i) {
                    float v = fmaxf(acc[rt][ct][i] + bv, 0.f);
                    s[i] += v * wv;
                }
            }
#pragma unroll
            for (int i = 0; i < 4; ++i) {
#pragma unroll
                for (int mask = 1; mask < 16; mask <<= 1)
                    s[i] += __shfl_xor(s[i], mask, 64);
            }
            if (m16 == 0) {
#pragma unroll
                for (int i = 0; i < 4; ++i) {
                    int rowL = rt * 16 + quad * 4 + i;
                    psf[rowL * 4 + cg] = s[i];
                }
            }
        }
        __syncthreads();
        if (tid < 64) {
            int row = row0 + tid;
            if (row < NN)
                out[row] = (psf[tid * 4] + psf[tid * 4 + 1]) + (psf[tid * 4 + 2] + psf[tid * 4 + 3]) + b32[0];
        }
        return;
    }

    // ---- h1 = relu(acc+b1) -> fp16 into LDS col-slice (C-layout -> A-layout) ----
    __syncthreads();
#pragma unroll
    for (int rt = 0; rt < 4; ++rt) {
#pragma unroll
        for (int ct = 0; ct < 2; ++ct) {
            int col = cg * 32 + ct * 16 + m16;
            float bv = b1[col];
#pragma unroll
            for (int i = 0; i < 4; ++i) {
                int rL = rt * 16 + quad * 4 + i;
                float v = fmaxf(acc[rt][ct][i] + bv, 0.f);
                sA[rL * 128 + (((col >> 3) ^ (rL & 15)) << 3) + (col & 7)] = f2h(v);
            }
        }
    }
    __syncthreads();

    // ---- GEMM2 ----
    f32x4 acc2[4][2] = {};
#pragma unroll
    for (int ks = 0; ks < 4; ++ks) {
        f16x8 a[4];
#pragma unroll
        for (int rt = 0; rt < 4; ++rt) {
            int rowL = rt * 16 + m16;
            int u = ks * 4 + quad;
            a[rt] = *(const f16x8*)&sA[rowL * 128 + ((u ^ (rowL & 15)) << 3)];
        }
#pragma unroll
        for (int ct = 0; ct < 2; ++ct) {
            int widx = (cg * 32 + ct * 16 + m16) * 128 + ks * 32 + quad * 8;
            f16x8 b = *(const f16x8*)&W2[widx];
#pragma unroll
            for (int rt = 0; rt < 4; ++rt)
                acc2[rt][ct] = __builtin_amdgcn_mfma_f32_16x16x32_f16(a[rt], b, acc2[rt][ct], 0, 0, 0);
        }
    }

    // ---- epilogue: bias -> fp16 -> LDS -> plane-layout store ----
    __syncthreads();
#pragma unroll
    for (int rt = 0; rt < 4; ++rt) {
#pragma unroll
        for (int ct = 0; ct < 2; ++ct) {
            int col = cg * 32 + ct * 16 + m16;
            float bv = b2[col];
#pragma unroll
            for (int i = 0; i < 4; ++i) {
                int rL = rt * 16 + quad * 4 + i;
                float v = acc2[rt][ct][i] + bv;
                sA[rL * 128 + (((col >> 3) ^ (rL & 15)) << 3) + (col & 7)] = f2h(v);
            }
        }
    }
    __syncthreads();
#pragma unroll
    for (int it = 0; it < 2; ++it) {
        int unit = it * 256 + tid;
        int s = unit >> 6, r = unit & 63;
        int node = row0 + r;
        if (node < NN) {
            int u0 = 2 * s, u1 = 2 * s + 1;
            ushort8v v0 = *(const ushort8v*)&sA[r * 128 + ((u0 ^ (r & 15)) << 3)];
            ushort8v v1 = *(const ushort8v*)&sA[r * 128 + ((u1 ^ (r & 15)) << 3)];
            unsigned short* P = H + (size_t)s * PL + (size_t)node * 16;
            *(ushort8v*)&P[0] = v0;
            *(ushort8v*)&P[8] = v1;
        }
    }
}

// ---------------- launch ----------------
static inline size_t align256(size_t x) { return (x + 255) & ~(size_t)255; }

extern "C" void kernel_launch(void* const* d_in, const int* in_sizes, int n_in,
                              void* d_out, int out_size, void* d_ws, size_t ws_size,
                              hipStream_t stream) {
    const float* x   = (const float*)d_in[0];
    const int*   ei  = (const int*)d_in[1];
    const float* w11 = (const float*)d_in[2];
    const float* b11 = (const float*)d_in[3];
    const float* w12 = (const float*)d_in[4];
    const float* b12 = (const float*)d_in[5];
    const float* w21 = (const float*)d_in[6];
    const float* b21 = (const float*)d_in[7];
    const float* w22 = (const float*)d_in[8];
    const float* b22 = (const float*)d_in[9];
    const float* w31 = (const float*)d_in[10];
    const float* b31 = (const float*)d_in[11];
    const float* w32 = (const float*)d_in[12];
    const float* b32 = (const float*)d_in[13];
    float* out = (float*)d_out;

    const int* src = ei;
    const int* dst = ei + NE;

    char* ws = (char*)d_ws;
    size_t off = 0;
    unsigned short* Abuf = (unsigned short*)(ws + off); off += align256((size_t)NN * F * 2);
    unsigned short* Bbuf = (unsigned short*)(ws + off); off += align256((size_t)NN * F * 2);
    int* bcnt    = (int*)(ws + off); off += align256((size_t)NBUCK * 4);
    int* bbase   = (int*)(ws + off); off += align256((size_t)(NBUCK + 1) * 4);
    int* bcur    = (int*)(ws + off); off += align256((size_t)NBUCK * 4);
    int* row_ptr = (int*)(ws + off); off += align256((size_t)(NN + 1) * 4);
    int* csr     = (int*)(ws + off); off += align256((size_t)NE * 4);
    unsigned* scratch = (unsigned*)(ws + off); off += align256((size_t)NE * 4);
    unsigned short* wt[5];
    for (int i = 0; i < 5; ++i) {
        wt[i] = (unsigned short*)(ws + off); off += align256((size_t)128 * 128 * 2);
    }
    (void)ws_size;

    // ---- weight + input conversion ----
    WPack wp;
    wp.w[0] = w11; wp.w[1] = w12; wp.w[2] = w21; wp.w[3] = w22; wp.w[4] = w31;
    for (int i = 0; i < 5; ++i) wp.t[i] = wt[i];
    k_w2h<<<320, 256, 0, stream>>>(wp);
    k_x2h<<<NN * 16 / 256, 256, 0, stream>>>(x, Abuf);

    // ---- CSR build (bucket-level) ----
    (void)hipMemsetAsync(bcnt, 0, (size_t)NBUCK * 4, stream);
    k_bhist<<<256, 256, 0, stream>>>(dst, bcnt);
    k_bscan<<<1, 512, 0, stream>>>(bcnt, bbase, bcur);
    k_scatterA<<<256, 256, 0, stream>>>(src, dst, bcur, scratch);
    k_fillB<<<NBUCK, 256, 0, stream>>>(bbase, scratch, row_ptr, csr);

    const int aggBlocks = ((NN + 127) / 128) * 8;   // 782 node-blocks x 8 slices = 6256
    const int mlpBlocks = (NN + 63) / 64;           // 1563

    // ---- layer 1 ----
    k_agg<<<aggBlocks, 256, 0, stream>>>(Abuf, row_ptr, csr, Bbuf);
    k_mlp<0><<<mlpBlocks, 256, 0, stream>>>(Bbuf, wt[0], b11, wt[1], b12,
                                            nullptr, nullptr, Abuf, nullptr);
    // ---- layer 2 ----
    k_agg<<<aggBlocks, 256, 0, stream>>>(Abuf, row_ptr, csr, Bbuf);
    k_mlp<0><<<mlpBlocks, 256, 0, stream>>>(Bbuf, wt[2], b21, wt[3], b22,
                                            nullptr, nullptr, Abuf, nullptr);
    // ---- layer 3 ----
    k_agg<<<aggBlocks, 256, 0, stream>>>(Abuf, row_ptr, csr, Bbuf);
    k_mlp<1><<<mlpBlocks, 256, 0, stream>>>(Bbuf, wt[4], b31, nullptr, nullptr,
                                            w32, b32, nullptr, out);
}

// Round 13
// 412.310 us; speedup vs baseline: 1.1912x; 1.1912x over previous
//
#include <hip/hip_runtime.h>

#define NN 100000
#define NE 1600000
#define F 128
#define NBUCK ((NN + 255) >> 8)                         // 391 buckets of 256 nodes
#define EPB (NE / 256)                                  // 6250 edges per scatter block

typedef _Float16 f16x8 __attribute__((ext_vector_type(8)));
typedef float    f32x4 __attribute__((ext_vector_type(4)));
typedef unsigned short ushort8v __attribute__((ext_vector_type(8)));
typedef unsigned short ushort4v __attribute__((ext_vector_type(4)));

__device__ inline unsigned short f2h(float f) {
    _Float16 h = (_Float16)f;                       // RTN
    return __builtin_bit_cast(unsigned short, h);
}
__device__ inline float h2f(unsigned short u) {
    return (float)__builtin_bit_cast(_Float16, u);
}

// ---------------- CSR build (bucket-level only) ----------------
__global__ __launch_bounds__(256) void k_bhist(const int* __restrict__ dst, int* __restrict__ bcnt) {
    __shared__ int sc[NBUCK];
    for (int i = threadIdx.x; i < NBUCK; i += 256) sc[i] = 0;
    __syncthreads();
    int stride = gridDim.x * 256;
    for (int e = blockIdx.x * 256 + threadIdx.x; e < NE; e += stride)
        atomicAdd(&sc[dst[e] >> 8], 1);
    __syncthreads();
    for (int i = threadIdx.x; i < NBUCK; i += 256) {
        int c = sc[i];
        if (c) atomicAdd(&bcnt[i], c);
    }
}

__global__ void k_bscan(const int* __restrict__ bcnt, int* __restrict__ bbase, int* __restrict__ bcur) {
    __shared__ int s[512];
    int t = threadIdx.x;
    int v = (t < NBUCK) ? bcnt[t] : 0;
    s[t] = v;
    __syncthreads();
    for (int off = 1; off < 512; off <<= 1) {
        int u = (t >= off) ? s[t - off] : 0;
        __syncthreads();
        s[t] += u;
        __syncthreads();
    }
    int excl = s[t] - v;
    if (t < NBUCK) { bbase[t] = excl; bcur[t] = excl; }
    if (t == 0) bbase[NBUCK] = NE;
}

__global__ __launch_bounds__(256) void k_scatterA(const int* __restrict__ src,
                                                  const int* __restrict__ dst,
                                                  int* __restrict__ bcur,
                                                  unsigned* __restrict__ scratch) {
    __shared__ uint2 sEdge[EPB];          // 50 KB
    __shared__ int cnt[512];
    __shared__ int scn[512];
    __shared__ int cntB[512];
    __shared__ int gbase[512];
    __shared__ int ssum[256];

    const int tid = threadIdx.x;
    const int ebase = blockIdx.x * EPB;

#pragma unroll
    for (int i = tid; i < 512; i += 256) { cnt[i] = 0; cntB[i] = 0; }
    __syncthreads();

    for (int i = tid; i < EPB; i += 256) {
        int b = dst[ebase + i] >> 8;
        atomicAdd(&cnt[b], 1);
    }
    __syncthreads();

    int c0 = cnt[2 * tid], c1 = cnt[2 * tid + 1];
    ssum[tid] = c0 + c1;
    __syncthreads();
    for (int off = 1; off < 256; off <<= 1) {
        int v = (tid >= off) ? ssum[tid - off] : 0;
        __syncthreads();
        ssum[tid] += v;
        __syncthreads();
    }
    int texcl = (tid == 0) ? 0 : ssum[tid - 1];
    scn[2 * tid] = texcl;
    scn[2 * tid + 1] = texcl + c0;
#pragma unroll
    for (int i = tid; i < NBUCK; i += 256) {
        int c = cnt[i];
        gbase[i] = c ? atomicAdd(&bcur[i], c) : 0;
    }
    __syncthreads();

    for (int i = tid; i < EPB; i += 256) {
        int s = src[ebase + i], d = dst[ebase + i];
        int b = d >> 8;
        int rank = atomicAdd(&cntB[b], 1);
        sEdge[scn[b] + rank] = make_uint2((unsigned)s, (unsigned)d);
    }
    __syncthreads();

    for (int i = tid; i < EPB; i += 256) {
        uint2 ed = sEdge[i];
        int b = (int)(ed.y >> 8);
        unsigned w = ((ed.y & 255u) << 24) | ed.x;
        scratch[gbase[b] + (i - scn[b])] = w;
    }
}

__global__ __launch_bounds__(256) void k_fillB(const int* __restrict__ bbase,
                                               const unsigned* __restrict__ scratch,
                                               int* __restrict__ row_ptr,
                                               int* __restrict__ csr) {
    __shared__ int cnt[256];
    __shared__ int s[256];
    __shared__ int cur[256];
    int b = blockIdx.x;
    int base = bbase[b], end = bbase[b + 1];
    int t = threadIdx.x;
    cnt[t] = 0;
    __syncthreads();
    for (int i = base + t; i < end; i += 256)
        atomicAdd(&cnt[scratch[i] >> 24], 1);
    __syncthreads();
    int v = cnt[t];
    s[t] = v;
    __syncthreads();
    for (int off = 1; off < 256; off <<= 1) {
        int u = (t >= off) ? s[t - off] : 0;
        __syncthreads();
        s[t] += u;
        __syncthreads();
    }
    int excl = s[t] - v;
    int node = (b << 8) + t;
    if (node < NN) row_ptr[node] = base + excl;
    if (b == NBUCK - 1 && t == 0) row_ptr[NN] = NE;
    cur[t] = excl;
    __syncthreads();
    for (int i = base + t; i < end; i += 256) {
        unsigned w = scratch[i];
        int n = w >> 24;
        int p = atomicAdd(&cur[n], 1);
        csr[base + p] = (int)(w & 0xFFFFFFu);
    }
}

// ---------------- x -> fp16 (RTN), row-major ----------------
__global__ void k_x2h(const float* __restrict__ x, unsigned short* __restrict__ xh) {
    int idx = blockIdx.x * 256 + threadIdx.x;     // over float4s, NN*128/4 total
    float4 v = ((const float4*)x)[idx];
    ushort4v h;
    h.x = f2h(v.x);
    h.y = f2h(v.y);
    h.z = f2h(v.z);
    h.w = f2h(v.w);
    ((ushort4v*)xh)[idx] = h;
}

// ---------------- weight: W[k][n] fp32 -> Wt [n][k] fp16 ----------------
struct WPack {
    const float* w[5];
    unsigned short* t[5];
};

__global__ void k_w2h(WPack p) {
    int which = blockIdx.x >> 6;
    int idx = (blockIdx.x & 63) * 256 + threadIdx.x; // over n*128+k
    int n = idx >> 7, k = idx & 127;
    p.t[which][idx] = f2h(p.w[which][k * 128 + n]);
}

// ---------------- fused layer: gather (256B rows) + 2-GEMM MLP, 64-row tile ----------------
// Phase 1: 16 groups x 16 lanes; group gathers node rows (self + neighbors, fp32 acc,
//          8-way unroll) -> fp16 -> XOR-swizzled LDS A-tile.
// Phase 2: GEMM1 (4 col-slice waves) [+relu] -> LDS -> GEMM2 -> H row-major.
// L3==1: GEMM1 -> dot w32 -> out fp32.
template <int L3>
__global__ __launch_bounds__(256, 5) void k_layer(const unsigned short* __restrict__ G,
                                                  const int* __restrict__ row_ptr,
                                                  const int* __restrict__ csr,
                                                  const unsigned short* __restrict__ W1,
                                                  const float* __restrict__ b1,
                                                  const unsigned short* __restrict__ W2,
                                                  const float* __restrict__ b2,
                                                  const float* __restrict__ w32,
                                                  const float* __restrict__ b32,
                                                  unsigned short* __restrict__ H,
                                                  float* __restrict__ out) {
    __shared__ __align__(16) unsigned short sA[64 * 128];   // 16 KB

    const int tid = threadIdx.x;
    const int row0 = blockIdx.x * 64;
    const int cg   = tid >> 6;           // wave id = col slice 0..3
    const int lane = tid & 63;
    const int m16  = lane & 15;
    const int quad = lane >> 4;

    // ---- phase 1: gather into sA (16 lanes x 16B per node row) ----
    {
        const int g = tid >> 4;          // 0..15
        const int l16 = tid & 15;
        const int lofs = l16 * 8;
#pragma unroll
        for (int it = 0; it < 4; ++it) {
            int r = it * 16 + g;         // 0..63
            int node = row0 + r;
            float a[8] = {};
            if (node < NN) {
                ushort8v sh = *(const ushort8v*)&G[(size_t)node * F + lofs];
#pragma unroll
                for (int k = 0; k < 8; ++k) a[k] = h2f(sh[k]);
                int st = row_ptr[node], e = row_ptr[node + 1];
                int p = st;
                for (; p + 8 <= e; p += 8) {
                    ushort8v v[8];
#pragma unroll
                    for (int q = 0; q < 8; ++q) {
                        int j = csr[p + q];
                        v[q] = *(const ushort8v*)&G[(size_t)j * F + lofs];
                    }
#pragma unroll
                    for (int k = 0; k < 8; ++k) {
                        float t0 = (h2f(v[0][k]) + h2f(v[1][k])) + (h2f(v[2][k]) + h2f(v[3][k]));
                        float t1 = (h2f(v[4][k]) + h2f(v[5][k])) + (h2f(v[6][k]) + h2f(v[7][k]));
                        a[k] += t0 + t1;
                    }
                }
                if (p + 4 <= e) {
                    ushort8v v[4];
#pragma unroll
                    for (int q = 0; q < 4; ++q) {
                        int j = csr[p + q];
                        v[q] = *(const ushort8v*)&G[(size_t)j * F + lofs];
                    }
#pragma unroll
                    for (int k = 0; k < 8; ++k)
                        a[k] += (h2f(v[0][k]) + h2f(v[1][k])) + (h2f(v[2][k]) + h2f(v[3][k]));
                    p += 4;
                }
                if (p + 2 <= e) {
                    int j0 = csr[p], j1 = csr[p + 1];
                    ushort8v v0 = *(const ushort8v*)&G[(size_t)j0 * F + lofs];
                    ushort8v v1 = *(const ushort8v*)&G[(size_t)j1 * F + lofs];
#pragma unroll
                    for (int k = 0; k < 8; ++k) a[k] += h2f(v0[k]) + h2f(v1[k]);
                    p += 2;
                }
                if (p < e) {
                    int j0 = csr[p];
                    ushort8v v0 = *(const ushort8v*)&G[(size_t)j0 * F + lofs];
#pragma unroll
                    for (int k = 0; k < 8; ++k) a[k] += h2f(v0[k]);
                }
            }
            ushort8v o;
#pragma unroll
            for (int k = 0; k < 8; ++k) o[k] = f2h(a[k]);
            *(ushort8v*)&sA[r * 128 + ((l16 ^ (r & 15)) << 3)] = o;
        }
    }
    __syncthreads();

    // ---- GEMM1 (4 col-slice waves, 32 cols each) ----
    f32x4 acc[4][2] = {};
#pragma unroll
    for (int ks = 0; ks < 4; ++ks) {
        f16x8 a[4];
#pragma unroll
        for (int rt = 0; rt < 4; ++rt) {
            int rowL = rt * 16 + m16;
            int u = ks * 4 + quad;
            a[rt] = *(const f16x8*)&sA[rowL * 128 + ((u ^ (rowL & 15)) << 3)];
        }
#pragma unroll
        for (int ct = 0; ct < 2; ++ct) {
            int widx = (cg * 32 + ct * 16 + m16) * 128 + ks * 32 + quad * 8;
            f16x8 b = *(const f16x8*)&W1[widx];
#pragma unroll
            for (int rt = 0; rt < 4; ++rt)
                acc[rt][ct] = __builtin_amdgcn_mfma_f32_16x16x32_f16(a[rt], b, acc[rt][ct], 0, 0, 0);
        }
    }

    if (L3) {
        float* psf = (float*)sA;     // 64 rows x 4 cg
        __syncthreads();
#pragma unroll
        for (int rt = 0; rt < 4; ++rt) {
            float s[4] = {0.f, 0.f, 0.f, 0.f};
#pragma unroll
            for (int ct = 0; ct < 2; ++ct) {
                int col = cg * 32 + ct * 16 + m16;
                float bv = b1[col];
                float wv = w32[col];
#pragma unroll
                for (int i = 0; i < 4; ++i) {
                    float v = fmaxf(acc[rt][ct][i] + bv, 0.f);
                    s[i] += v * wv;
                }
            }
#pragma unroll
            for (int i = 0; i < 4; ++i) {
#pragma unroll
                for (int mask = 1; mask < 16; mask <<= 1)
                    s[i] += __shfl_xor(s[i], mask, 64);
            }
            if (m16 == 0) {
#pragma unroll
                for (int i = 0; i < 4; ++i) {
                    int rowL = rt * 16 + quad * 4 + i;
                    psf[rowL * 4 + cg] = s[i];
                }
            }
        }
        __syncthreads();
        if (tid < 64) {
            int row = row0 + tid;
            if (row < NN)
                out[row] = (psf[tid * 4] + psf[tid * 4 + 1]) + (psf[tid * 4 + 2] + psf[tid * 4 + 3]) + b32[0];
        }
        return;
    }

    // ---- h1 = relu(acc+b1) -> fp16 into LDS col-slice (C-layout -> A-layout) ----
    __syncthreads();
#pragma unroll
    for (int rt = 0; rt < 4; ++rt) {
#pragma unroll
        for (int ct = 0; ct < 2; ++ct) {
            int col = cg * 32 + ct * 16 + m16;
            float bv = b1[col];
#pragma unroll
            for (int i = 0; i < 4; ++i) {
                int rL = rt * 16 + quad * 4 + i;
                float v = fmaxf(acc[rt][ct][i] + bv, 0.f);
                sA[rL * 128 + (((col >> 3) ^ (rL & 15)) << 3) + (col & 7)] = f2h(v);
            }
        }
    }
    __syncthreads();

    // ---- GEMM2 ----
    f32x4 acc2[4][2] = {};
#pragma unroll
    for (int ks = 0; ks < 4; ++ks) {
        f16x8 a[4];
#pragma unroll
        for (int rt = 0; rt < 4; ++rt) {
            int rowL = rt * 16 + m16;
            int u = ks * 4 + quad;
            a[rt] = *(const f16x8*)&sA[rowL * 128 + ((u ^ (rowL & 15)) << 3)];
        }
#pragma unroll
        for (int ct = 0; ct < 2; ++ct) {
            int widx = (cg * 32 + ct * 16 + m16) * 128 + ks * 32 + quad * 8;
            f16x8 b = *(const f16x8*)&W2[widx];
#pragma unroll
            for (int rt = 0; rt < 4; ++rt)
                acc2[rt][ct] = __builtin_amdgcn_mfma_f32_16x16x32_f16(a[rt], b, acc2[rt][ct], 0, 0, 0);
        }
    }

    // ---- epilogue: bias -> fp16 -> LDS -> coalesced row-major store ----
    __syncthreads();
#pragma unroll
    for (int rt = 0; rt < 4; ++rt) {
#pragma unroll
        for (int ct = 0; ct < 2; ++ct) {
            int col = cg * 32 + ct * 16 + m16;
            float bv = b2[col];
#pragma unroll
            for (int i = 0; i < 4; ++i) {
                int rL = rt * 16 + quad * 4 + i;
                float v = acc2[rt][ct][i] + bv;
                sA[rL * 128 + (((col >> 3) ^ (rL & 15)) << 3) + (col & 7)] = f2h(v);
            }
        }
    }
    __syncthreads();
    {
        ushort8v* go = (ushort8v*)(H + (size_t)row0 * F);
#pragma unroll
        for (int i = 0; i < 4; ++i) {
            int fg = i * 256 + tid;
            int r = fg >> 4, u = fg & 15;
            if (row0 + r < NN)
                go[fg] = *(const ushort8v*)&sA[r * 128 + ((u ^ (r & 15)) << 3)];
        }
    }
}

// ---------------- launch ----------------
static inline size_t align256(size_t x) { return (x + 255) & ~(size_t)255; }

extern "C" void kernel_launch(void* const* d_in, const int* in_sizes, int n_in,
                              void* d_out, int out_size, void* d_ws, size_t ws_size,
                              hipStream_t stream) {
    const float* x   = (const float*)d_in[0];
    const int*   ei  = (const int*)d_in[1];
    const float* w11 = (const float*)d_in[2];
    const float* b11 = (const float*)d_in[3];
    const float* w12 = (const float*)d_in[4];
    const float* b12 = (const float*)d_in[5];
    const float* w21 = (const float*)d_in[6];
    const float* b21 = (const float*)d_in[7];
    const float* w22 = (const float*)d_in[8];
    const float* b22 = (const float*)d_in[9];
    const float* w31 = (const float*)d_in[10];
    const float* b31 = (const float*)d_in[11];
    const float* w32 = (const float*)d_in[12];
    const float* b32 = (const float*)d_in[13];
    float* out = (float*)d_out;

    const int* src = ei;
    const int* dst = ei + NE;

    char* ws = (char*)d_ws;
    size_t off = 0;
    unsigned short* Abuf = (unsigned short*)(ws + off); off += align256((size_t)NN * F * 2);
    unsigned short* Bbuf = (unsigned short*)(ws + off); off += align256((size_t)NN * F * 2);
    int* bcnt    = (int*)(ws + off); off += align256((size_t)NBUCK * 4);
    int* bbase   = (int*)(ws + off); off += align256((size_t)(NBUCK + 1) * 4);
    int* bcur    = (int*)(ws + off); off += align256((size_t)NBUCK * 4);
    int* row_ptr = (int*)(ws + off); off += align256((size_t)(NN + 1) * 4);
    int* csr     = (int*)(ws + off); off += align256((size_t)NE * 4);
    unsigned* scratch = (unsigned*)(ws + off); off += align256((size_t)NE * 4);
    unsigned short* wt[5];
    for (int i = 0; i < 5; ++i) {
        wt[i] = (unsigned short*)(ws + off); off += align256((size_t)128 * 128 * 2);
    }
    (void)ws_size;

    // ---- weight + input conversion ----
    WPack wp;
    wp.w[0] = w11; wp.w[1] = w12; wp.w[2] = w21; wp.w[3] = w22; wp.w[4] = w31;
    for (int i = 0; i < 5; ++i) wp.t[i] = wt[i];
    k_w2h<<<320, 256, 0, stream>>>(wp);
    k_x2h<<<(NN * F / 4 + 255) / 256, 256, 0, stream>>>(x, Abuf);

    // ---- CSR build (bucket-level) ----
    (void)hipMemsetAsync(bcnt, 0, (size_t)NBUCK * 4, stream);
    k_bhist<<<256, 256, 0, stream>>>(dst, bcnt);
    k_bscan<<<1, 512, 0, stream>>>(bcnt, bbase, bcur);
    k_scatterA<<<256, 256, 0, stream>>>(src, dst, bcur, scratch);
    k_fillB<<<NBUCK, 256, 0, stream>>>(bbase, scratch, row_ptr, csr);

    const int layerBlocks = (NN + 63) / 64;     // 1563

    // ---- layer 1: Abuf -> Bbuf ----
    k_layer<0><<<layerBlocks, 256, 0, stream>>>(Abuf, row_ptr, csr,
                                                wt[0], b11, wt[1], b12,
                                                nullptr, nullptr, Bbuf, nullptr);
    // ---- layer 2: Bbuf -> Abuf ----
    k_layer<0><<<layerBlocks, 256, 0, stream>>>(Bbuf, row_ptr, csr,
                                                wt[2], b21, wt[3], b22,
                                                nullptr, nullptr, Abuf, nullptr);
    // ---- layer 3: Abuf -> out ----
    k_layer<1><<<layerBlocks, 256, 0, stream>>>(Abuf, row_ptr, csr,
                                                wt[4], b31, nullptr, nullptr,
                                                w32, b32, nullptr, out);
}